// Round 4
// baseline (36.855 us; speedup 1.0000x reference)
//
#include <hip/hip_runtime.h>

#define BB 2
#define SDIM 1024
#define DDIM 128
#define TILE 64
#define K1_ROWS 4

#define F4GET(v,k) ((k)==0?(v).x:((k)==1?(v).y:((k)==2?(v).z:(v).w)))

typedef float f2 __attribute__((ext_vector_type(2)));

// B-side swizzled LDS float4 pointer: quad-column XOR with (row>>2)&7.
// With the consecutive-4 j-mapping (rows tx*4+c), all 16 lanes of a read map
// to 8 distinct bank quads (2-way = free), and the 4 per-thread B rows share
// one swizzle term (tx&7) so inner-loop B addressing is ~2 VALU ops/iter.
__device__ __forceinline__ float4* ldsB_ptr4(float* base, int row, int c4) {
    int swz = c4 ^ ((row >> 2) & 7);
    return reinterpret_cast<float4*>(base + row * DDIM + swz * 4);
}

// ---------------- Kernel 1: projections + row dot products ----------------
// (unchanged from R3 for attribution)
__global__ __launch_bounds__(256) void proj_kernel(
    const float* __restrict__ x, const float* __restrict__ W1,
    const float* __restrict__ b1, const float* __restrict__ W2,
    const float* __restrict__ b2,
    float* __restrict__ hi, float* __restrict__ hjb,
    float* __restrict__ si2, float* __restrict__ sj2)
{
    __shared__ float sX[K1_ROWS][DDIM];
    __shared__ float sRed[4][K1_ROWS];
    const int tid  = threadIdx.x;
    const int d    = tid & 127;
    const int half = tid >> 7;
    const int r0   = blockIdx.x * K1_ROWS;

    if (tid < K1_ROWS * DDIM / 4) {
        reinterpret_cast<float4*>(&sX[0][0])[tid] =
            reinterpret_cast<const float4*>(x + (size_t)r0 * DDIM)[tid];
    }
    __syncthreads();

    const float* Wh = W1 + (size_t)half * DDIM * DDIM;

    float acc[K1_ROWS];
    #pragma unroll
    for (int r = 0; r < K1_ROWS; ++r) acc[r] = 0.f;

    for (int k = 0; k < DDIM; k += 4) {
        float4 xv[K1_ROWS];
        #pragma unroll
        for (int r = 0; r < K1_ROWS; ++r)
            xv[r] = *reinterpret_cast<const float4*>(&sX[r][k]);
        #pragma unroll
        for (int kk = 0; kk < 4; ++kk) {
            float w = Wh[(size_t)(k + kk) * DDIM + d];
            #pragma unroll
            for (int r = 0; r < K1_ROWS; ++r)
                acc[r] = fmaf(F4GET(xv[r], kk), w, acc[r]);
        }
    }

    if (half) {
        const float bv = b1[d];
        #pragma unroll
        for (int r = 0; r < K1_ROWS; ++r) acc[r] += bv;
    }

    float* hout = half ? hjb : hi;
    #pragma unroll
    for (int r = 0; r < K1_ROWS; ++r)
        hout[(size_t)(r0 + r) * DDIM + d] = acc[r];

    const float wv   = W2[d];
    const int   lane = tid & 63;
    const int   wave = tid >> 6;
    #pragma unroll
    for (int r = 0; r < K1_ROWS; ++r) {
        float v = acc[r] * wv;
        #pragma unroll
        for (int off = 32; off >= 1; off >>= 1)
            v += __shfl_xor(v, off, 64);
        if (lane == 0) sRed[wave][r] = v;
    }
    __syncthreads();
    if (tid < K1_ROWS) {
        si2[r0 + tid] = 0.5f * (sRed[0][tid] + sRed[1][tid]);
    } else if (tid < 2 * K1_ROWS) {
        int r = tid - K1_ROWS;
        sj2[r0 + r] = 0.5f * (sRed[2][r] + sRed[3][r]) + b2[0];
    }
}

// ---------------- Kernel 2: pairwise edge logits ----------------
// out[b,i,j] = si2[b,i] + sj2[b,j] + sum_d |hi[b,i,d] + hjb[b,j,d]| * 0.5*w2[d]
// Thread (tx,ty): i-rows ty*4..+3, j-cols tx*4..+3 (consecutive -> float4 store).
// sHi UNSWIZZLED: A-reads are 16-lane broadcasts (4 distinct addrs); addresses
// are base + compile-time immediates -> zero inner-loop VALU for A and W.
__global__ __launch_bounds__(256) void edge_kernel(
    const float* __restrict__ hi, const float* __restrict__ hjb,
    const float* __restrict__ si2, const float* __restrict__ sj2,
    const float* __restrict__ W2, float* __restrict__ out)
{
    __shared__ float sHi[TILE * DDIM];
    __shared__ float sHj[TILE * DDIM];
    __shared__ float sW[DDIM];
    __shared__ float sSi[TILE];
    __shared__ float sSj[TILE];

    const int b   = blockIdx.z;
    const int i0  = blockIdx.y * TILE;
    const int j0  = blockIdx.x * TILE;
    const int tid = threadIdx.x;

    const float4* src_i = reinterpret_cast<const float4*>(hi  + ((size_t)b * SDIM + i0) * DDIM);
    const float4* src_j = reinterpret_cast<const float4*>(hjb + ((size_t)b * SDIM + j0) * DDIM);
    #pragma unroll
    for (int p = 0; p < 8; ++p) {
        int idx = p * 256 + tid;
        reinterpret_cast<float4*>(sHi)[idx] = src_i[idx];   // linear
        int row = idx >> 5, c4 = idx & 31;
        *ldsB_ptr4(sHj, row, c4) = src_j[idx];              // swizzled
    }
    if (tid < DDIM) {
        sW[tid] = 0.5f * W2[tid];
    } else if (tid < DDIM + TILE) {
        sSi[tid - DDIM] = si2[b * SDIM + i0 + (tid - DDIM)];
    } else {
        sSj[tid - DDIM - TILE] = sj2[b * SDIM + j0 + (tid - DDIM - TILE)];
    }
    __syncthreads();

    const int tx = tid & 15;   // j sub-block: cols tx*4 .. tx*4+3
    const int ty = tid >> 4;   // i sub-block: rows ty*4 .. ty*4+3
    const int ri = ty * 4;
    const int rbj = tx & 7;    // shared B swizzle term for all 4 B rows

    f2 acc[4][4];
    #pragma unroll
    for (int r = 0; r < 4; ++r)
        #pragma unroll
        for (int c = 0; c < 4; ++c) acc[r][c] = (f2){0.f, 0.f};

    const float* pA = sHi + ri * DDIM;         // + r*DDIM + dc4*4 (immediates)
    const float* pB = sHj + (tx * 4) * DDIM;   // + c*DDIM + sw

    #pragma unroll 4
    for (int dc4 = 0; dc4 < 32; ++dc4) {
        const int sw = ((dc4 ^ rbj) << 2);
        float4 Bv[4];
        #pragma unroll
        for (int c = 0; c < 4; ++c)
            Bv[c] = *reinterpret_cast<const float4*>(pB + c * DDIM + sw);
        const float4 wv = *reinterpret_cast<const float4*>(sW + dc4 * 4);

        #pragma unroll
        for (int r = 0; r < 4; ++r) {
            const float4 A = *reinterpret_cast<const float4*>(pA + r * DDIM + dc4 * 4);
            const f2 a01 = {A.x, A.y};
            const f2 a23 = {A.z, A.w};
            #pragma unroll
            for (int c = 0; c < 4; ++c) {
                const f2 b01 = {Bv[c].x, Bv[c].y};
                const f2 b23 = {Bv[c].z, Bv[c].w};
                f2 t0 = a01 + b01;   // v_pk_add_f32
                f2 t1 = a23 + b23;   // v_pk_add_f32
                acc[r][c].x = fmaf(fabsf(t0.x), wv.x, acc[r][c].x);
                acc[r][c].y = fmaf(fabsf(t0.y), wv.y, acc[r][c].y);
                acc[r][c].x = fmaf(fabsf(t1.x), wv.z, acc[r][c].x);
                acc[r][c].y = fmaf(fabsf(t1.y), wv.w, acc[r][c].y);
            }
        }
    }

    #pragma unroll
    for (int r = 0; r < 4; ++r) {
        const float sv = sSi[ri + r];
        float4 o;
        o.x = acc[r][0].x + acc[r][0].y + sv + sSj[tx * 4 + 0];
        o.y = acc[r][1].x + acc[r][1].y + sv + sSj[tx * 4 + 1];
        o.z = acc[r][2].x + acc[r][2].y + sv + sSj[tx * 4 + 2];
        o.w = acc[r][3].x + acc[r][3].y + sv + sSj[tx * 4 + 3];
        size_t base = (size_t)b * SDIM * SDIM + (size_t)(i0 + ri + r) * SDIM + j0 + tx * 4;
        *reinterpret_cast<float4*>(out + base) = o;
    }
}

extern "C" void kernel_launch(void* const* d_in, const int* in_sizes, int n_in,
                              void* d_out, int out_size, void* d_ws, size_t ws_size,
                              hipStream_t stream) {
    const float* x  = (const float*)d_in[0];
    const float* W1 = (const float*)d_in[1];
    const float* b1 = (const float*)d_in[2];
    const float* W2 = (const float*)d_in[3];
    const float* b2 = (const float*)d_in[4];
    float* out = (float*)d_out;

    float* ws  = (float*)d_ws;
    float* hi  = ws;                                    // B*S*D
    float* hjb = ws + (size_t)BB * SDIM * DDIM;         // B*S*D
    float* si2 = ws + (size_t)2 * BB * SDIM * DDIM;     // B*S
    float* sj2 = si2 + (size_t)BB * SDIM;               // B*S

    proj_kernel<<<BB * SDIM / K1_ROWS, 256, 0, stream>>>(x, W1, b1, W2, b2, hi, hjb, si2, sj2);
    edge_kernel<<<dim3(SDIM / TILE, SDIM / TILE, BB), 256, 0, stream>>>(hi, hjb, si2, sj2, W2, out);
}